// Round 3
// baseline (6388.134 us; speedup 1.0000x reference)
//
#include <hip/hip_runtime.h>
#include <cstddef>

#define TSTEPS 365
#define NGRID_ 2000
#define NX_ 16
#define H_ 256
#define CPB 32
#define NBLK ((NGRID_ + CPB - 1) / CPB)   // 63 blocks, 512 threads each

typedef __attribute__((ext_vector_type(8))) short short8v;
typedef __attribute__((ext_vector_type(4))) float f32x4;

__device__ __forceinline__ unsigned short f2bf(float f) {
    unsigned int u = __float_as_uint(f);
    u += 0x7fffu + ((u >> 16) & 1u);   // round-to-nearest-even
    return (unsigned short)(u >> 16);
}
__device__ __forceinline__ float bf2f(unsigned short s) {
    return __uint_as_float(((unsigned int)s) << 16);
}
__device__ __forceinline__ float sigmoid_f(float v) {
    return 1.0f / (1.0f + __expf(-v));
}
__device__ __forceinline__ float tanh_f(float v) {
    return 1.0f - 2.0f / (__expf(2.0f * v) + 1.0f);
}

// ---------------------------------------------------------------------------
// Pack wh [4][256][256] and wx [4][16][256] (fp32) into bf16 MFMA B-fragment
// order (identical layout to round 2 — validated).
// ---------------------------------------------------------------------------
#define WH_WORDS (64 * 8 * 64)
#define WX_WORDS (64 * 64)

__global__ __launch_bounds__(256) void pack_weights(
    const float* __restrict__ wh, const float* __restrict__ wx,
    unsigned short* __restrict__ pb)
{
    int tid = blockIdx.x * 256 + threadIdx.x;
    short8v sv;
    if (tid < WH_WORDS) {
        int lane = tid & 63;
        int kt   = (tid >> 6) & 7;
        int gu   = tid >> 9;
        int g    = gu >> 4;
        int ncol = ((gu & 15) << 4) | (lane & 15);
        int kb   = kt * 32 + ((lane >> 4) << 3);
#pragma unroll
        for (int j = 0; j < 8; ++j)
            sv[j] = (short)f2bf(wh[((size_t)(g * H_ + kb + j)) * H_ + ncol]);
        *(short8v*)(pb + (size_t)tid * 8) = sv;
    } else if (tid < WH_WORDS + WX_WORDS) {
        int t2   = tid - WH_WORDS;
        int lane = t2 & 63;
        int gu   = t2 >> 6;
        int g    = gu >> 4;
        int ncol = ((gu & 15) << 4) | (lane & 15);
        int kkb  = (lane >> 4) << 3;
#pragma unroll
        for (int j = 0; j < 8; ++j) {
            int k = (kkb + j) & 15;
            sv[j] = (short)f2bf(wx[((size_t)(g * NX_ + k)) * H_ + ncol]);
        }
        *(short8v*)(pb + (size_t)tid * 8) = sv;
    }
}

// ---------------------------------------------------------------------------
// Persistent LSTM. Block = 32 cells (2 cell-tiles), 8 waves. Wave w owns
// units [w*32, w*32+32) for all 4 gates. Each wh B-chunk is loaded once and
// feeds BOTH cell-tiles. wx B-fragments pinned in VGPRs for all 365 steps.
// wh stream double-buffered across kt rounds; kt=7 prefetches next step kt=0.
// ---------------------------------------------------------------------------
__global__ __launch_bounds__(512, 2) void lstm_mfma(
    const float* __restrict__ x,     // [T][NGRID][NX]
    const float* __restrict__ b,     // [4][H]
    const float* __restrict__ wlin,  // [H]
    const float* __restrict__ blin,  // [1]
    const unsigned short* __restrict__ pb,
    float* __restrict__ out)         // [T][NGRID]
{
    __shared__ __align__(16) unsigned short Ah[2][2][32][16][8];  // 32 KB
    __shared__ __align__(16) unsigned short Al[2][2][32][16][8];  // 32 KB
    __shared__ __align__(16) unsigned short Ax[2][2][4][16][8];   // 8 KB
    __shared__ float red[2][8][2][16];                            // 4 KB

    const int tid = threadIdx.x;
    const int w   = tid >> 6;
    const int l   = tid & 63;
    const int lg  = l >> 4;
    const int ln  = l & 15;
    const int c0  = blockIdx.x * CPB;

    float bias[4][2], wl[2];
#pragma unroll
    for (int g = 0; g < 4; ++g)
#pragma unroll
        for (int ut = 0; ut < 2; ++ut)
            bias[g][ut] = b[g * H_ + w * 32 + ut * 16 + ln];
    wl[0] = wlin[w * 32 + ln];
    wl[1] = wlin[w * 32 + 16 + ln];
    const float bl = blin[0];

    const unsigned short* BX = pb + (size_t)WH_WORDS * 8;

    // zero h(-1) buffers (buf 0, both cell-tiles): 16 KB each = 1024 uint4
    {
        uint4 z = make_uint4(0, 0, 0, 0);
#pragma unroll
        for (int i = 0; i < 2; ++i) {
            ((uint4*)Ah)[tid + i * 512] = z;
            ((uint4*)Al)[tid + i * 512] = z;
        }
    }
    // stage x(0): 512 threads = 32 cells x 16 features
    {
        const int cell = tid >> 4, nx = tid & 15;
        const int gc = c0 + cell;
        float v = (gc < NGRID_) ? x[(size_t)gc * NX_ + nx] : 0.0f;
        unsigned short hi = f2bf(v);
        unsigned short lo = f2bf(v - bf2f(hi));
        Ax[0][cell >> 4][nx >> 3][cell & 15][nx & 7] = hi;
        Ax[0][cell >> 4][2 + (nx >> 3)][cell & 15][nx & 7] = lo;
    }

    // B preloads: kt=0 wh chunks + permanent wx chunks
    short8v bbA[8], bbB[8], bx[8];
#pragma unroll
    for (int i = 0; i < 8; ++i) {
        int gu = ((i >> 1) << 4) | (w * 2 + (i & 1));
        bbA[i] = *(const short8v*)(pb + (((size_t)gu * 8 + 0) * 64 + l) * 8);
        bx[i]  = *(const short8v*)(BX + ((size_t)gu * 64 + l) * 8);
    }

    __syncthreads();

    f32x4 acc0[8], acc1[8];
    float cst[2][2][4];
#pragma unroll
    for (int ct = 0; ct < 2; ++ct)
#pragma unroll
        for (int ut = 0; ut < 2; ++ut)
#pragma unroll
            for (int r = 0; r < 4; ++r) cst[ct][ut][r] = 0.0f;

#define KT_ROUND(KT, CUR, NXT, LOADKT)                                         \
    {                                                                          \
        _Pragma("unroll")                                                      \
        for (int i = 0; i < 8; ++i) {                                          \
            int gu = ((i >> 1) << 4) | (w * 2 + (i & 1));                      \
            NXT[i] = *(const short8v*)(pb + (((size_t)gu * 8 + (LOADKT)) * 64 + l) * 8); \
        }                                                                      \
        short8v ah0 = *(const short8v*)&Ah[rb][0][(KT) * 4 + lg][ln][0];       \
        short8v al0 = *(const short8v*)&Al[rb][0][(KT) * 4 + lg][ln][0];       \
        short8v ah1 = *(const short8v*)&Ah[rb][1][(KT) * 4 + lg][ln][0];       \
        short8v al1 = *(const short8v*)&Al[rb][1][(KT) * 4 + lg][ln][0];       \
        _Pragma("unroll")                                                      \
        for (int i = 0; i < 8; ++i) {                                          \
            acc0[i] = __builtin_amdgcn_mfma_f32_16x16x32_bf16(ah0, CUR[i], acc0[i], 0, 0, 0); \
            acc0[i] = __builtin_amdgcn_mfma_f32_16x16x32_bf16(al0, CUR[i], acc0[i], 0, 0, 0); \
            acc1[i] = __builtin_amdgcn_mfma_f32_16x16x32_bf16(ah1, CUR[i], acc1[i], 0, 0, 0); \
            acc1[i] = __builtin_amdgcn_mfma_f32_16x16x32_bf16(al1, CUR[i], acc1[i], 0, 0, 0); \
        }                                                                      \
    }

#pragma unroll 1
    for (int t = 0; t < TSTEPS; ++t) {
        const int rb = t & 1, wb = rb ^ 1;

#pragma unroll
        for (int i = 0; i < 8; ++i) {
            float bv = bias[i >> 1][i & 1];
            f32x4 a0 = {bv, bv, bv, bv};
            acc0[i] = a0;
            acc1[i] = a0;
        }

        KT_ROUND(0, bbA, bbB, 1)
        KT_ROUND(1, bbB, bbA, 2)
        KT_ROUND(2, bbA, bbB, 3)
        KT_ROUND(3, bbB, bbA, 4)
        KT_ROUND(4, bbA, bbB, 5)
        KT_ROUND(5, bbB, bbA, 6)
        KT_ROUND(6, bbA, bbB, 7)
        KT_ROUND(7, bbB, bbA, 0)   // prefetch next step's kt=0 into bbA

        // x projection round (B pinned in registers)
        {
            short8v ax0 = *(const short8v*)&Ax[rb][0][lg][ln][0];
            short8v ax1 = *(const short8v*)&Ax[rb][1][lg][ln][0];
#pragma unroll
            for (int i = 0; i < 8; ++i) {
                acc0[i] = __builtin_amdgcn_mfma_f32_16x16x32_bf16(ax0, bx[i], acc0[i], 0, 0, 0);
                acc1[i] = __builtin_amdgcn_mfma_f32_16x16x32_bf16(ax1, bx[i], acc1[i], 0, 0, 0);
            }
        }

        // gates + state + publish h + output partials, per cell-tile
#define GATES(ACC, CT)                                                         \
        {                                                                      \
            float hN[2][4];                                                    \
            _Pragma("unroll")                                                  \
            for (int ut = 0; ut < 2; ++ut)                                     \
                _Pragma("unroll")                                              \
                for (int r = 0; r < 4; ++r) {                                  \
                    float ig = sigmoid_f(ACC[0 * 2 + ut][r]);                  \
                    float fg = sigmoid_f(ACC[1 * 2 + ut][r]);                  \
                    float gt = tanh_f(ACC[2 * 2 + ut][r]);                     \
                    float og = sigmoid_f(ACC[3 * 2 + ut][r]);                  \
                    float c  = fmaf(fg, cst[CT][ut][r], ig * gt);              \
                    cst[CT][ut][r] = c;                                        \
                    hN[ut][r] = og * tanh_f(c);                                \
                }                                                              \
            _Pragma("unroll")                                                  \
            for (int ut = 0; ut < 2; ++ut) {                                   \
                int u = w * 32 + ut * 16 + ln;                                 \
                _Pragma("unroll")                                              \
                for (int r = 0; r < 4; ++r) {                                  \
                    int cell = lg * 4 + r;                                     \
                    unsigned short hi = f2bf(hN[ut][r]);                       \
                    Ah[wb][CT][u >> 3][cell][u & 7] = hi;                      \
                    Al[wb][CT][u >> 3][cell][u & 7] = f2bf(hN[ut][r] - bf2f(hi)); \
                }                                                              \
            }                                                                  \
            float p[4];                                                        \
            _Pragma("unroll")                                                  \
            for (int r = 0; r < 4; ++r) {                                      \
                p[r] = fmaf(hN[0][r], wl[0], hN[1][r] * wl[1]);                \
                _Pragma("unroll")                                              \
                for (int off = 1; off < 16; off <<= 1)                         \
                    p[r] += __shfl_xor(p[r], off);                             \
            }                                                                  \
            if (ln == 0) {                                                     \
                _Pragma("unroll")                                              \
                for (int r = 0; r < 4; ++r) red[rb][w][CT][lg * 4 + r] = p[r]; \
            }                                                                  \
        }

        GATES(acc0, 0)
        GATES(acc1, 1)

        // stage x(t+1)
        if (t + 1 < TSTEPS) {
            const int cell = tid >> 4, nx = tid & 15;
            const int gc = c0 + cell;
            float v = (gc < NGRID_)
                          ? x[(((size_t)(t + 1)) * NGRID_ + gc) * NX_ + nx]
                          : 0.0f;
            unsigned short hi = f2bf(v);
            unsigned short lo = f2bf(v - bf2f(hi));
            Ax[wb][cell >> 4][nx >> 3][cell & 15][nx & 7] = hi;
            Ax[wb][cell >> 4][2 + (nx >> 3)][cell & 15][nx & 7] = lo;
        }

        __syncthreads();

        if (tid < CPB) {
            const int gc = c0 + tid;
            if (gc < NGRID_) {
                float s = bl;
#pragma unroll
                for (int w2 = 0; w2 < 8; ++w2)
                    s += red[rb][w2][tid >> 4][tid & 15];
                out[(size_t)t * NGRID_ + gc] = s;
            }
        }
    }
#undef KT_ROUND
#undef GATES
}

extern "C" void kernel_launch(void* const* d_in, const int* in_sizes, int n_in,
                              void* d_out, int out_size, void* d_ws, size_t ws_size,
                              hipStream_t stream) {
    const float* x    = (const float*)d_in[0];
    const float* wx   = (const float*)d_in[1];
    const float* wh   = (const float*)d_in[2];
    const float* b    = (const float*)d_in[3];
    const float* wlin = (const float*)d_in[4];
    const float* blin = (const float*)d_in[5];
    float* out = (float*)d_out;
    unsigned short* pb = (unsigned short*)d_ws;   // 576 KB

    hipLaunchKernelGGL(pack_weights, dim3((WH_WORDS + WX_WORDS) / 256), dim3(256),
                       0, stream, wh, wx, pb);
    hipLaunchKernelGGL(lstm_mfma, dim3(NBLK), dim3(512), 0, stream,
                       x, b, wlin, blin, pb, out);
}